// Round 1
// 102.962 us; speedup vs baseline: 1.0174x; 1.0174x over previous
//
#include <hip/hip_runtime.h>
#include <math.h>

#define NPTS 8192
#define NB 4
#define BLK 256
#define Q 8            // queries per thread (processed as 4 packed pairs)
#define TILE 512       // ref points staged in LDS per tile (duplicated: 16 KB)

typedef __attribute__((ext_vector_type(2))) float v2f;
typedef __attribute__((ext_vector_type(4))) float v4f;

// packed fp32 FMA: d.x = a.x*b.x+c.x ; d.y = a.y*b.y+c.y (one VOP3P inst)
__device__ __forceinline__ v2f pk_fma(v2f a, v2f b, v2f c) {
    v2f d;
    asm("v_pk_fma_f32 %0, %1, %2, %3" : "=v"(d) : "v"(a), "v"(b), "v"(c));
    return d;
}
// 3-input min in one inst
__device__ __forceinline__ float min3f(float a, float b, float c) {
    float d;
    asm("v_min3_f32 %0, %1, %2, %3" : "=v"(d) : "v"(a), "v"(b), "v"(c));
    return d;
}

// Kernel 1: for each (batch,dir) and each query point, compute
//   partial[bd][seg][q] = min over refs in segment of (|r|^2 - 2 q.r)
// (|q|^2 added later; min commutes with the +|q|^2 and the clamp.)
__global__ __launch_bounds__(BLK) void chamfer_partial(
    const float* __restrict__ tmpl, const float* __restrict__ src,
    float* __restrict__ partial, int seg_len, int nseg)
{
    // per ref, duplicated for packed math:
    //   lds[i][0] = (-2rx, -2rx, -2ry, -2ry)
    //   lds[i][1] = (-2rz, -2rz, |r|^2, |r|^2)
    __shared__ v4f lds[TILE][2];
    const int bd  = blockIdx.z;          // 0..7 = b*2 + dir
    const int b   = bd >> 1;
    const int dir = bd & 1;
    const float* qp = (dir ? src : tmpl) + (size_t)b * NPTS * 3;
    const float* rp = (dir ? tmpl : src) + (size_t)b * NPTS * 3;
    const int tid   = threadIdx.x;
    const int qbase = blockIdx.x * (BLK * Q);

    v2f qx[Q / 2], qy[Q / 2], qz[Q / 2];
    float mn[Q];
#pragma unroll
    for (int p = 0; p < Q / 2; p++) {
        const int qi0 = qbase + (2 * p) * BLK + tid;
        const int qi1 = qbase + (2 * p + 1) * BLK + tid;
        qx[p] = (v2f){qp[3 * qi0 + 0], qp[3 * qi1 + 0]};
        qy[p] = (v2f){qp[3 * qi0 + 1], qp[3 * qi1 + 1]};
        qz[p] = (v2f){qp[3 * qi0 + 2], qp[3 * qi1 + 2]};
        mn[2 * p]     = 3.4e38f;
        mn[2 * p + 1] = 3.4e38f;
    }

    const int seg_start = blockIdx.y * seg_len;
    for (int ts = 0; ts < seg_len; ts += TILE) {
        __syncthreads();
        for (int i = tid; i < TILE; i += BLK) {
            const int ri = seg_start + ts + i;
            const float rx = rp[3 * ri + 0];
            const float ry = rp[3 * ri + 1];
            const float rz = rp[3 * ri + 2];
            const float mx = -2.f * rx, my = -2.f * ry, mz = -2.f * rz;
            const float w  = fmaf(rx, rx, fmaf(ry, ry, rz * rz));
            lds[i][0] = (v4f){mx, mx, my, my};
            lds[i][1] = (v4f){mz, mz, w, w};
        }
        __syncthreads();
        // process refs two at a time: 24 pk_fma + 8 min3 per 16 evals
#pragma unroll 2
        for (int j = 0; j < TILE; j += 2) {
            const v4f A0 = lds[j][0];      // (-2rx,-2rx,-2ry,-2ry) ref a
            const v4f A1 = lds[j][1];      // (-2rz,-2rz, wa, wa)
            const v4f B0 = lds[j + 1][0];  // ref b
            const v4f B1 = lds[j + 1][1];
            const v2f axx = A0.lo, ayy = A0.hi, azz = A1.lo, aww = A1.hi;
            const v2f bxx = B0.lo, byy = B0.hi, bzz = B1.lo, bww = B1.hi;
#pragma unroll
            for (int p = 0; p < Q / 2; p++) {
                v2f ta = pk_fma(qx[p], axx, aww);
                ta = pk_fma(qy[p], ayy, ta);
                ta = pk_fma(qz[p], azz, ta);
                v2f tb = pk_fma(qx[p], bxx, bww);
                tb = pk_fma(qy[p], byy, tb);
                tb = pk_fma(qz[p], bzz, tb);
                mn[2 * p]     = min3f(mn[2 * p],     ta.x, tb.x);
                mn[2 * p + 1] = min3f(mn[2 * p + 1], ta.y, tb.y);
            }
        }
    }

    const size_t base = ((size_t)bd * nseg + blockIdx.y) * NPTS;
#pragma unroll
    for (int k = 0; k < Q; k++)
        partial[base + qbase + k * BLK + tid] = mn[k];
}

// Kernel 2: combine segment partials, add |q|^2, clamp, sqrt, global mean.
__global__ __launch_bounds__(BLK) void chamfer_reduce(
    const float* __restrict__ tmpl, const float* __restrict__ src,
    const float* __restrict__ partial, float* __restrict__ out, int nseg)
{
    const int t  = blockIdx.x * BLK + threadIdx.x;  // 0 .. 8*NPTS-1
    const int bd = t >> 13;                         // / NPTS
    const int qi = t & (NPTS - 1);
    const int b  = bd >> 1;
    const int dir = bd & 1;
    const float* qp = (dir ? src : tmpl) + (size_t)b * NPTS * 3;
    const float qx = qp[3 * qi + 0];
    const float qy = qp[3 * qi + 1];
    const float qz = qp[3 * qi + 2];
    const float sq = qx * qx + qy * qy + qz * qz;

    float m = 3.4e38f;
    for (int s = 0; s < nseg; s++)
        m = fminf(m, partial[((size_t)bd * nseg + s) * NPTS + qi]);

    float v = sqrtf(fmaxf(sq + m, 0.f));

    // wave reduction (64 lanes)
#pragma unroll
    for (int off = 32; off > 0; off >>= 1)
        v += __shfl_down(v, off, 64);

    __shared__ float wsum[BLK / 64];
    const int lane = threadIdx.x & 63;
    const int wid  = threadIdx.x >> 6;
    if (lane == 0) wsum[wid] = v;
    __syncthreads();
    if (threadIdx.x == 0) {
        float s = 0.f;
#pragma unroll
        for (int w = 0; w < BLK / 64; w++) s += wsum[w];
        // mean over N (8192) * avg 2 dirs * mean 4 batches = /65536
        atomicAdd(out, s * (1.0f / 65536.0f));
    }
}

extern "C" void kernel_launch(void* const* d_in, const int* in_sizes, int n_in,
                              void* d_out, int out_size, void* d_ws, size_t ws_size,
                              hipStream_t stream) {
    const float* tmpl = (const float*)d_in[0];
    const float* src  = (const float*)d_in[1];
    float* out      = (float*)d_out;
    float* partial  = (float*)d_ws;

    // choose nseg (power of 2) to fit workspace: need 8*nseg*NPTS*4 bytes
    int nseg = 16;
    while (nseg > 1 && (size_t)8 * nseg * NPTS * sizeof(float) > ws_size)
        nseg >>= 1;
    const int seg_len = NPTS / nseg;

    hipMemsetAsync(d_out, 0, sizeof(float), stream);

    dim3 g1(NPTS / (BLK * Q), nseg, 2 * NB);
    chamfer_partial<<<g1, BLK, 0, stream>>>(tmpl, src, partial, seg_len, nseg);

    chamfer_reduce<<<(2 * NB * NPTS) / BLK, BLK, 0, stream>>>(tmpl, src, partial, out, nseg);
}

// Round 2
// 100.757 us; speedup vs baseline: 1.0396x; 1.0219x over previous
//
#include <hip/hip_runtime.h>
#include <math.h>

#define NPTS 8192
#define NB 4
#define BLK 256
#define Q 8            // queries per thread (processed as 4 packed pairs)
#define TILE 512       // ref points staged in LDS per tile (8 KB as float4)

typedef __attribute__((ext_vector_type(2))) float v2f;
typedef __attribute__((ext_vector_type(4))) float v4f;

// Packed fp32 FMA variants using op_sel broadcasts (VOP3P dword selects).
// Semantics: D.lo = S0[opsel0]*S1[opsel1]+S2[opsel2];
//            D.hi = S0[opselhi0]*S1[opselhi1]+S2[opselhi2]
// where [0]=lo dword, [1]=hi dword of the 64-bit source.

// t = bcast_lo(a) * q + bcast_hi(c)    (x*q + w in one op)
__device__ __forceinline__ v2f pk_fma_xw(v2f a, v2f q, v2f c) {
    v2f d;
    asm("v_pk_fma_f32 %0, %1, %2, %3 op_sel:[0,0,1] op_sel_hi:[0,1,1]"
        : "=v"(d) : "v"(a), "v"(q), "v"(c));
    return d;
}
// t = bcast_hi(a) * q + t              (y*q + t)
__device__ __forceinline__ v2f pk_fma_bhi(v2f a, v2f q, v2f c) {
    v2f d;
    asm("v_pk_fma_f32 %0, %1, %2, %3 op_sel:[1,0,0] op_sel_hi:[1,1,1]"
        : "=v"(d) : "v"(a), "v"(q), "v"(c));
    return d;
}
// t = bcast_lo(a) * q + t              (z*q + t)
__device__ __forceinline__ v2f pk_fma_blo(v2f a, v2f q, v2f c) {
    v2f d;
    asm("v_pk_fma_f32 %0, %1, %2, %3 op_sel:[0,0,0] op_sel_hi:[0,1,1]"
        : "=v"(d) : "v"(a), "v"(q), "v"(c));
    return d;
}
// 3-input min in one inst
__device__ __forceinline__ float min3f(float a, float b, float c) {
    float d;
    asm("v_min3_f32 %0, %1, %2, %3" : "=v"(d) : "v"(a), "v"(b), "v"(c));
    return d;
}

// Kernel 1: for each (batch,dir) and each query point, compute
//   partial[bd][seg][q] = min over refs in segment of (|r|^2 - 2 q.r)
// (|q|^2 added later; min commutes with the +|q|^2 and the clamp.)
// Refs staged in LDS as (rx, ry, rz, |r|^2); the -2 is folded into the
// query registers (exact pow2 scale, bitwise-identical products).
__global__ __launch_bounds__(BLK) void chamfer_partial(
    const float* __restrict__ tmpl, const float* __restrict__ src,
    float* __restrict__ partial, int seg_len, int nseg)
{
    __shared__ v4f lds[TILE];
    const int bd  = blockIdx.z;          // 0..7 = b*2 + dir
    const int b   = bd >> 1;
    const int dir = bd & 1;
    const float* qp = (dir ? src : tmpl) + (size_t)b * NPTS * 3;
    const float* rp = (dir ? tmpl : src) + (size_t)b * NPTS * 3;
    const int tid   = threadIdx.x;
    const int qbase = blockIdx.x * (BLK * Q);

    v2f qx[Q / 2], qy[Q / 2], qz[Q / 2];
    float mn[Q];
#pragma unroll
    for (int p = 0; p < Q / 2; p++) {
        const int qi0 = qbase + (2 * p) * BLK + tid;
        const int qi1 = qbase + (2 * p + 1) * BLK + tid;
        qx[p] = (v2f){-2.f * qp[3 * qi0 + 0], -2.f * qp[3 * qi1 + 0]};
        qy[p] = (v2f){-2.f * qp[3 * qi0 + 1], -2.f * qp[3 * qi1 + 1]};
        qz[p] = (v2f){-2.f * qp[3 * qi0 + 2], -2.f * qp[3 * qi1 + 2]};
        mn[2 * p]     = 3.4e38f;
        mn[2 * p + 1] = 3.4e38f;
    }

    const int seg_start = blockIdx.y * seg_len;
    for (int ts = 0; ts < seg_len; ts += TILE) {
        __syncthreads();
        for (int i = tid; i < TILE; i += BLK) {
            const int ri = seg_start + ts + i;
            const float rx = rp[3 * ri + 0];
            const float ry = rp[3 * ri + 1];
            const float rz = rp[3 * ri + 2];
            const float w  = fmaf(rx, rx, fmaf(ry, ry, rz * rz));
            lds[i] = (v4f){rx, ry, rz, w};
        }
        __syncthreads();
        // 2 refs/iter: 2 ds_read_b128 + 24 pk_fma + 8 min3 per 16 evals
#pragma unroll 4
        for (int j = 0; j < TILE; j += 2) {
            const v4f A = lds[j];
            const v4f B = lds[j + 1];
            const v2f Axy = A.lo, Azw = A.hi;
            const v2f Bxy = B.lo, Bzw = B.hi;
#pragma unroll
            for (int p = 0; p < Q / 2; p++) {
                v2f ta = pk_fma_xw (Axy, qx[p], Azw);  // x*qx + w
                ta     = pk_fma_bhi(Axy, qy[p], ta);   // y*qy + t
                ta     = pk_fma_blo(Azw, qz[p], ta);   // z*qz + t
                v2f tb = pk_fma_xw (Bxy, qx[p], Bzw);
                tb     = pk_fma_bhi(Bxy, qy[p], tb);
                tb     = pk_fma_blo(Bzw, qz[p], tb);
                mn[2 * p]     = min3f(mn[2 * p],     ta.x, tb.x);
                mn[2 * p + 1] = min3f(mn[2 * p + 1], ta.y, tb.y);
            }
        }
    }

    const size_t base = ((size_t)bd * nseg + blockIdx.y) * NPTS;
#pragma unroll
    for (int k = 0; k < Q; k++)
        partial[base + qbase + k * BLK + tid] = mn[k];
}

// Kernel 2: combine segment partials, add |q|^2, clamp, sqrt, global mean.
__global__ __launch_bounds__(BLK) void chamfer_reduce(
    const float* __restrict__ tmpl, const float* __restrict__ src,
    const float* __restrict__ partial, float* __restrict__ out, int nseg)
{
    const int t  = blockIdx.x * BLK + threadIdx.x;  // 0 .. 8*NPTS-1
    const int bd = t >> 13;                         // / NPTS
    const int qi = t & (NPTS - 1);
    const int b  = bd >> 1;
    const int dir = bd & 1;
    const float* qp = (dir ? src : tmpl) + (size_t)b * NPTS * 3;
    const float qx = qp[3 * qi + 0];
    const float qy = qp[3 * qi + 1];
    const float qz = qp[3 * qi + 2];
    const float sq = qx * qx + qy * qy + qz * qz;

    float m = 3.4e38f;
    for (int s = 0; s < nseg; s++)
        m = fminf(m, partial[((size_t)bd * nseg + s) * NPTS + qi]);

    float v = sqrtf(fmaxf(sq + m, 0.f));

    // wave reduction (64 lanes)
#pragma unroll
    for (int off = 32; off > 0; off >>= 1)
        v += __shfl_down(v, off, 64);

    __shared__ float wsum[BLK / 64];
    const int lane = threadIdx.x & 63;
    const int wid  = threadIdx.x >> 6;
    if (lane == 0) wsum[wid] = v;
    __syncthreads();
    if (threadIdx.x == 0) {
        float s = 0.f;
#pragma unroll
        for (int w = 0; w < BLK / 64; w++) s += wsum[w];
        // mean over N (8192) * avg 2 dirs * mean 4 batches = /65536
        atomicAdd(out, s * (1.0f / 65536.0f));
    }
}

extern "C" void kernel_launch(void* const* d_in, const int* in_sizes, int n_in,
                              void* d_out, int out_size, void* d_ws, size_t ws_size,
                              hipStream_t stream) {
    const float* tmpl = (const float*)d_in[0];
    const float* src  = (const float*)d_in[1];
    float* out      = (float*)d_out;
    float* partial  = (float*)d_ws;

    // choose nseg (power of 2) to fit workspace: need 8*nseg*NPTS*4 bytes
    int nseg = 16;
    while (nseg > 1 && (size_t)8 * nseg * NPTS * sizeof(float) > ws_size)
        nseg >>= 1;
    const int seg_len = NPTS / nseg;

    hipMemsetAsync(d_out, 0, sizeof(float), stream);

    dim3 g1(NPTS / (BLK * Q), nseg, 2 * NB);
    chamfer_partial<<<g1, BLK, 0, stream>>>(tmpl, src, partial, seg_len, nseg);

    chamfer_reduce<<<(2 * NB * NPTS) / BLK, BLK, 0, stream>>>(tmpl, src, partial, out, nseg);
}